// Round 4
// 4635.872 us; speedup vs baseline: 1.1046x; 1.1046x over previous
//
#include <hip/hip_runtime.h>
#include <stdint.h>

typedef unsigned short ushort_t;
typedef unsigned int uint32;

#define SEQ   2048
#define BATCH 64
#define INDIM 128
#define HID   256
#define NGRP  4         // independent batch groups (16 rows each)
#define NWGG  16        // WGs per group (16 hidden cols each)
#define HSZ   (BATCH*SEQ*HID)

typedef __attribute__((ext_vector_type(8))) short short8;
typedef __attribute__((ext_vector_type(4))) float float4_t;
typedef __attribute__((ext_vector_type(2))) uint32 uint2_t;

__device__ __forceinline__ ushort_t f2bf(float f) {
  uint32 u = __builtin_bit_cast(uint32, f);
  u += 0x7FFFu + ((u >> 16) & 1u);           // round-to-nearest-even
  return (ushort_t)(u >> 16);
}
__device__ __forceinline__ float fast_sigmoid(float x) {
  return 1.0f / (1.0f + __expf(-x));
}
__device__ __forceinline__ float fast_tanh(float x) {
  return 1.0f - 2.0f / (__expf(2.0f * x) + 1.0f);
}
template<int CTRL>
__device__ __forceinline__ float bcast_quad(float v) {
  int r = __builtin_amdgcn_mov_dpp(__builtin_bit_cast(int, v), CTRL, 0xF, 0xF, true);
  return __builtin_bit_cast(float, r);
}

// Bypass (sc0 sc1) ops: coherent via the memory-side Infinity Cache.
// Identical instruction forms to the round-0 harness-verified kernel.
__device__ __forceinline__ void load16_bypass(short8& d, const ushort_t* p) {
  asm volatile("global_load_dwordx4 %0, %1, off sc0 sc1"
               : "=v"(d) : "v"(p) : "memory");
}
__device__ __forceinline__ void store_short_bypass(ushort_t* p, uint32 v) {
  asm volatile("global_store_short %0, %1, off sc0 sc1"
               :: "v"(p), "v"(v) : "memory");
}
__device__ __forceinline__ void store_dword_bypass(uint32* p, uint32 v) {
  asm volatile("global_store_dword %0, %1, off sc0 sc1"
               :: "v"(p), "v"(v) : "memory");
}
__device__ __forceinline__ void issue_poll(uint32& v, const uint32* p) {
  asm volatile("global_load_dword %0, %1, off sc0 sc1"
               : "=v"(v) : "v"(p) : "memory");
}
__device__ __forceinline__ void wait_vm1(uint32& v) {
  asm volatile("s_waitcnt vmcnt(1)" : "+v"(v) :: "memory");
}
__device__ __forceinline__ void drain_tied2(uint32& a, uint32& b) {
  // settle dangling poll loads BEFORE their VGPRs can be reused
  asm volatile("s_waitcnt vmcnt(0)" : "+v"(a), "+v"(b) :: "memory");
}
__device__ __forceinline__ void wait8(short8* c) {
  asm volatile("s_waitcnt vmcnt(0)"
               : "+v"(c[0]), "+v"(c[1]), "+v"(c[2]), "+v"(c[3]),
                 "+v"(c[4]), "+v"(c[5]), "+v"(c[6]), "+v"(c[7])
               :: "memory");
}
__device__ __forceinline__ void drain_vm() {
  asm volatile("s_waitcnt vmcnt(0)" ::: "memory");
}

// ---------------------------------------------------------------------------
// Pack kernel (identical to the round-0 harness-verified packing).
// hpub layout (uint2 = 8B of 4 bf16 cols), per (grp,buf) 1024 units:
//   unit idx = (s>>1)*32 + row*2 + (s&1), slice s = hidden-quad 0..63
//   -> consumer reads 16B = slices {2sh,2sh+1} of one row = 8 contiguous k.
// flags[grp*64 + s] = number of steps slice s has published (zeroed here).
// ---------------------------------------------------------------------------
__global__ void pack_init(const float* __restrict__ x,
                          const float* __restrict__ Wf, const float* __restrict__ Wi,
                          const float* __restrict__ Wo, const float* __restrict__ Wc,
                          const float* __restrict__ Uf, const float* __restrict__ Ui,
                          const float* __restrict__ Uo, const float* __restrict__ Uc,
                          const float* __restrict__ bf_, const float* __restrict__ bi_,
                          const float* __restrict__ bo_, const float* __restrict__ bc_,
                          ushort_t* __restrict__ BM2, float* __restrict__ bp2,
                          ushort_t* __restrict__ xbf, uint32* __restrict__ flags) {
  int idx = blockIdx.x * 256 + threadIdx.x;   // exactly SEQ*BATCH*INDIM threads
  {
    int e = idx & 7, lane = (idx >> 3) & 63, q = (idx >> 9) & 3,
        grp = (idx >> 11) & 3, t = idx >> 13;
    if (t < SEQ) {
      int row = grp * 16 + (lane & 15);
      int k = q * 32 + (lane >> 4) * 8 + e;
      xbf[idx] = f2bf(x[(row * SEQ + t) * INDIM + k]);
    }
  }
  if (idx < 64 * 12 * 512) {                  // B fragments
    int e = idx & 7, lane = (idx >> 3) & 63;
    int kf = (idx >> 9) % 12, jw = (idx >> 9) / 12;
    int w = jw & 3, j = jw >> 2;
    int llo = lane & 15, lhi = lane >> 4;
    int n = j * 16 + w * 4 + (llo >> 2);
    int g = llo & 3;
    int k = kf * 32 + lhi * 8 + e;
    const float* W4[4] = {Wf, Wi, Wo, Wc};
    const float* U4[4] = {Uf, Ui, Uo, Uc};
    float v = (k < HID) ? W4[g][k * HID + n] : U4[g][(k - HID) * HID + n];
    BM2[idx] = f2bf(v);
  }
  if (idx < 1024) {                           // packed bias
    int llo = idx & 15, jw = idx >> 4;
    int w = jw & 3, j = jw >> 2;
    int n = j * 16 + w * 4 + (llo >> 2);
    int g = llo & 3;
    const float* B4[4] = {bf_, bi_, bo_, bc_};
    bp2[idx] = B4[g][n];
  }
  if (idx < NGRP * 64) flags[idx] = 0;
}

// ---------------------------------------------------------------------------
// Persistent recurrence, barrier-free. 64 WGs x 256 thr = 256 independent
// waves. Group i = blockIdx&3 (16 batch rows); wave owns slice j*4+wave
// (4 hidden cols x 4 gates). Sync protocol = round-0 verified: publish data
// (sc0 sc1) -> vmcnt(0) drain -> flag store -> consumers poll flags -> wide
// fetch. Changes vs round-0 (all protocol-neutral):
//  * publish is transpose-free: each lane owns exactly one (row,col) of h_t
//    (quad-replicated gate rows; lane picks r==Lr) and stores one bf16 (2B)
//    at the byte address the old shfl-transpose produced. No shfl anywhere.
//  * pipelined double-poll: 2 outstanding flag loads, alternate vmcnt(1)
//    waits -> retry quantization ~halved; no s_sleep.
//  * dual-accumulator h-MFMA: two 4-deep chains instead of one 8-deep.
// ---------------------------------------------------------------------------
__global__ __launch_bounds__(256, 1) void lstm_seq(
    const ushort_t* __restrict__ xbf, const ushort_t* __restrict__ BM2,
    const float* __restrict__ bp2, uint2_t* hpub, uint32* flags,
    float* __restrict__ out)
{
  const int i    = blockIdx.x & 3;
  const int j    = blockIdx.x >> 2;
  const int tid  = threadIdx.x;
  const int wave = tid >> 6;
  const int lane = tid & 63;
  const int lhi  = lane >> 4;
  const int llo  = lane & 15;
  const int Lr   = lane & 3;           // gate row within the quad this lane owns
  const int csub = llo >> 2;           // hidden col within the slice
  const int row  = lhi * 4 + Lr;       // batch row (0..15) this lane publishes

  // persistent B fragments (48 VGPRs, all 2048 steps)
  short8 bfrag[12];
  {
    const ushort_t* bsrc = BM2 + (size_t)((j * 4 + wave) * 12) * 512 + lane * 8;
#pragma unroll
    for (int kf = 0; kf < 12; ++kf)
      bfrag[kf] = *(const short8*)(bsrc + kf * 512);
  }
  const float bias = bp2[(j * 4 + wave) * 16 + llo];

  float c_reg[4] = {0.f, 0.f, 0.f, 0.f};
  const int sown = j * 4 + wave;                    // owned slice
  const int colg = sown * 4 + csub;                 // global hidden col
  uint32* myflag = &flags[(i << 6) + sown];
  const uint32* pollp = &flags[(i << 6) + lane];

  // x fragments for t=0
  short8 xq[4];
  {
    const ushort_t* xs = xbf + (size_t)i * 2048 + lane * 8;
#pragma unroll
    for (int q = 0; q < 4; ++q) xq[q] = *(const short8*)(xs + q * 512);
  }

  for (int t = 0; t < SEQ; ++t) {
    // --- x part: independent of h ---
    float4_t acc = {bias, bias, bias, bias};
#pragma unroll
    for (int q = 0; q < 4; ++q)
      acc = __builtin_amdgcn_mfma_f32_16x16x32_bf16(xq[q], bfrag[8 + q], acc, 0, 0, 0);
    float4_t accA = {0.f, 0.f, 0.f, 0.f};
    float4_t accB = {0.f, 0.f, 0.f, 0.f};

    if (t > 0) {
      // --- pipelined double-poll: all 64 slices of my group at step >= t ---
      const uint32 want = (uint32)t;
      uint32 va, vb;
      issue_poll(va, pollp);
      issue_poll(vb, pollp);
      for (;;) {
        wait_vm1(va);                              // oldest outstanding done
        if (__all((int)(va >= want))) break;
        issue_poll(va, pollp);
        wait_vm1(vb);
        if (__all((int)(vb >= want))) break;
        issue_poll(vb, pollp);
      }
      drain_tied2(va, vb);                         // settle dangling poll load
      // --- wide fetch (once): h_{t-1} A-fragments, 8 x 16B bypass ---
      const ushort_t* hb = (const ushort_t*)
          (hpub + (size_t)(i * 2 + ((t - 1) & 1)) * 1024);
      short8 hf[8];
#pragma unroll
      for (int kf = 0; kf < 8; ++kf)
        load16_bypass(hf[kf], hb + (((kf * 4 + lhi) * 16 + llo) * 2) * 4);
      wait8(hf);
      // dual-accumulator: two 4-deep dependent MFMA chains
#pragma unroll
      for (int kf = 0; kf < 4; ++kf) {
        accA = __builtin_amdgcn_mfma_f32_16x16x32_bf16(hf[2 * kf],     bfrag[2 * kf],     accA, 0, 0, 0);
        accB = __builtin_amdgcn_mfma_f32_16x16x32_bf16(hf[2 * kf + 1], bfrag[2 * kf + 1], accB, 0, 0, 0);
      }
    }

    // --- gates (all four sigmoid, per ref) + cell update ---
    float hv0, hv1, hv2, hv3;
#pragma unroll
    for (int r = 0; r < 4; ++r) {
      float s  = fast_sigmoid(acc[r] + accA[r] + accB[r]);
      float fv = bcast_quad<0x00>(s);
      float iv = bcast_quad<0x55>(s);
      float ov = bcast_quad<0xAA>(s);
      float cv = bcast_quad<0xFF>(s);
      float cn = fv * c_reg[r] + iv * cv;
      c_reg[r] = cn;
      float h  = ov * fast_tanh(cn);
      if      (r == 0) hv0 = h;
      else if (r == 1) hv1 = h;
      else if (r == 2) hv2 = h;
      else             hv3 = h;
    }
    // lane's published value: h[row][colg] (quad lanes hold identical hv;
    // lane picks its gate-row r = Lr -> rows lhi*4+0..3 all covered)
    float val = (Lr == 0) ? hv0 : (Lr == 1) ? hv1 : (Lr == 2) ? hv2 : hv3;

    if (t < SEQ - 1) {
      // publish h_t: one bf16 (2B) per lane, same bytes as round-0 layout
      ushort_t* hbo = (ushort_t*)(hpub + (size_t)(i * 2 + (t & 1)) * 1024);
      store_short_bypass(hbo + ((sown >> 1) * 32 + row * 2 + (sown & 1)) * 4 + csub,
                         (uint32)f2bf(val));
      drain_vm();                                  // publish retired (wave-wide)
      if (lane == 0)
        store_dword_bypass(myflag, (uint32)(t + 1));
      // out store + x prefetch: off the critical path, after the flag
      out[((size_t)(16 * i + row) * SEQ + t) * HID + colg] = val;
      const ushort_t* xs = xbf + (size_t)((t + 1) * 4 + i) * 2048 + lane * 8;
#pragma unroll
      for (int q = 0; q < 4; ++q) xq[q] = *(const short8*)(xs + q * 512);
    } else {
      // final step: hidden_seq row + h_T + c_T (scatter, one value per lane)
      out[((size_t)(16 * i + row) * SEQ + t) * HID + colg] = val;
      out[HSZ + (size_t)(16 * i + row) * HID + colg] = val;
      float cva = (Lr == 0) ? c_reg[0] : (Lr == 1) ? c_reg[1]
                : (Lr == 2) ? c_reg[2] : c_reg[3];
      out[HSZ + BATCH * HID + (size_t)(16 * i + row) * HID + colg] = cva;
    }
  }
}

// ---------------------------------------------------------------------------
// Workspace layout (bytes) — identical to round 0:
//   [0, 786432)          BM2   bf16 wave-linear B fragments
//   [786432, 790528)     bp2   fp32 1024
//   [790528, 856064)     hpub  4 grp x 2 buf x 1024 units x 8B = 64KB
//   [856064, 857088)     flags u32 4 grp x 64 slices
//   [1048576, 34603008)  xbf   bf16 fragment-linear x (33.5 MB)
// ---------------------------------------------------------------------------
extern "C" void kernel_launch(void* const* d_in, const int* in_sizes, int n_in,
                              void* d_out, int out_size, void* d_ws, size_t ws_size,
                              hipStream_t stream) {
  const float* xp  = (const float*)d_in[0];
  const float* Uf  = (const float*)d_in[1];
  const float* Wf  = (const float*)d_in[2];
  const float* bf_ = (const float*)d_in[3];
  const float* Ui  = (const float*)d_in[4];
  const float* Wi  = (const float*)d_in[5];
  const float* bi_ = (const float*)d_in[6];
  const float* Uo  = (const float*)d_in[7];
  const float* Wo  = (const float*)d_in[8];
  const float* bo_ = (const float*)d_in[9];
  const float* Uc  = (const float*)d_in[10];
  const float* Wc  = (const float*)d_in[11];
  const float* bc_ = (const float*)d_in[12];

  char* ws = (char*)d_ws;
  ushort_t* BM2   = (ushort_t*)(ws);
  float*    bp2   = (float*)(ws + 786432);
  uint2_t*  hpub  = (uint2_t*)(ws + 790528);
  uint32*   flags = (uint32*)(ws + 856064);
  ushort_t* xbf   = (ushort_t*)(ws + 1048576);
  float*    out   = (float*)d_out;

  pack_init<<<65536, 256, 0, stream>>>(xp, Wf, Wi, Wo, Wc, Uf, Ui, Uo, Uc,
                                       bf_, bi_, bo_, bc_, BM2, bp2, xbf, flags);
  lstm_seq<<<NGRP * NWGG, 256, 0, stream>>>(xbf, BM2, bp2, hpub, flags, out);
}